// Round 5
// baseline (236.535 us; speedup 1.0000x reference)
//
#include <hip/hip_runtime.h>

// ---------------------------------------------------------------------------
// ConvFeatureExtractor: profile = rownorm( freq @ softmax(matches/T, axis=1)^T )
//   matches[f,i] = Thi[f, i>>6] + Tlo[f, i&63]  (separable!), F=8192, M=4096,
//   B=1024, K=6.  =>  probs[f,i] = e1[f,i>>6] * e2[f,i&63],  Z = (sum e1)(sum e2).
// R11: remove the LDS convoy entirely. R6-R10 all pinned at 35-39% MfmaUtil:
//   the A-tile LDS stage (shared across n-split waves) forces a barrier+vmcnt
//   convoy per kt, and each staged element is only reused 4x. New split: waves
//   own M-rows (wave tile 16m x 64n). The MFMA A-frag (row=l16, k=quad*8+e)
//   is then a DIRECT contiguous 16B global load -- no LDS / barriers / GLD16.
//   Cross-block A-reuse lives in the XCD-pinned L2 (remap: XCD k owns m-strips
//   {2k,2k+1} = 1MB slice; 1GB L2 traffic at ~21 TB/s agg < 34.5 ceiling).
//   16 independent free-running wave-streams per CU; per kt per wave:
//   2 global b128 (a-frags, prefetched 1 iter ahead) + 4 e1 dwords + 8 MFMA
//   (chains of 2, C=0) + 8 pk_fma (e1 fold, f32).
//   Also: cast+tables merged into one prep kernel (launch-overhead probe).
// ---------------------------------------------------------------------------

typedef __bf16  bf16x8 __attribute__((ext_vector_type(8)));
typedef float   f32x4  __attribute__((ext_vector_type(4)));

__device__ __forceinline__ short f2bf(float x) {
  unsigned u = __float_as_uint(x);
  unsigned r = (u + 0x7fffu + ((u >> 16) & 1u)) >> 16;   // RNE
  return (short)r;
}

__device__ __forceinline__ float wave_max(float v) {
  #pragma unroll
  for (int off = 32; off; off >>= 1) v = fmaxf(v, __shfl_xor(v, off, 64));
  return v;
}
__device__ __forceinline__ float wave_sum(float v) {
  #pragma unroll
  for (int off = 32; off; off >>= 1) v += __shfl_xor(v, off, 64);
  return v;
}

// ---------------- k1: prep = cast (blocks 0..4095) + tables (4096..6143) ----
// cast: freq f32 -> bf16 (4 elems/thread).
// tables: one wave per filter f:
//   Thi_l = P[d0*6+0]+P[d1*6+1]+P[d2*6+2], Tlo_l = P[d0*6+3]+P[d1*6+4]+P[d2*6+5]
//   e1 = exp((Thi-mxhi)/T), e2 = exp((Tlo-mxlo)/T), Z=(sum e1)(sum e2);
//   E1t[hi][f] = e1*invZ (transposed for coalesced gemm reads), E2[f][lo] = e2.
__global__ __launch_bounds__(256) void prep_kernel(const float* __restrict__ freq,
                                                   short* __restrict__ freqb,
                                                   const float* __restrict__ kp,
                                                   const float* __restrict__ temp,
                                                   float* __restrict__ E1t,
                                                   float* __restrict__ E2) {
  if (blockIdx.x < 4096) {
    int idx = blockIdx.x * 256 + threadIdx.x;
    float4 v = ((const float4*)freq)[idx];
    short4 o;
    o.x = f2bf(v.x); o.y = f2bf(v.y); o.z = f2bf(v.z); o.w = f2bf(v.w);
    ((short4*)freqb)[idx] = o;
  } else {
    const int t = threadIdx.x;
    const int lane = t & 63, wave = t >> 6;
    const int f = (blockIdx.x - 4096) * 4 + wave;
    const float* P = kp + f * 24;
    const int d0 = (lane >> 4) & 3, d1 = (lane >> 2) & 3, d2 = lane & 3;
    const float thi = P[d0 * 6 + 0] + P[d1 * 6 + 1] + P[d2 * 6 + 2];
    const float tlo = P[d0 * 6 + 3] + P[d1 * 6 + 4] + P[d2 * 6 + 5];
    const float mxhi = wave_max(thi), mxlo = wave_max(tlo);
    const float invT = 1.0f / temp[0];
    const float e1 = __expf((thi - mxhi) * invT);
    const float e2 = __expf((tlo - mxlo) * invT);
    const float s1 = wave_sum(e1), s2 = wave_sum(e2);
    const float invZ = 1.0f / (s1 * s2);
    E1t[lane * 8192 + f] = e1 * invZ;
    E2[(size_t)f * 64 + lane] = e2;
  }
}

// ---------------- k2: GEMM pooled = A(1024x4096) * B^T, B[f,i]=e1[f,i>>6]e2[f,i&63]
// Re-associated: pooled = sum_kt e1'[f,kt] * (A_kt x e2). Block 64m x 64n,
// 4 waves split M (wave = 16m x 64n = 1x4 frags of 16x16x32). NO LDS.
// A-frags loaded directly from global (16B/lane, L2-resident by XCD remap).
// Grid 2048 = 8/CU-queued, 4 resident (VGPR-limited ~16 waves/CU).
__global__ __launch_bounds__(256, 4) void gemm_kernel(const short* __restrict__ A,
                                                      const float* __restrict__ E1t,
                                                      const float* __restrict__ E2,
                                                      float* __restrict__ C) {
  const int t = threadIdx.x;
  const int lane = t & 63, wave = t >> 6;
  const int quad = lane >> 4, l16 = lane & 15;

  // XCD-aware remap: XCD k = d%8 owns L in [256k, 256k+256) = m-strips
  // {2k,2k+1} (n-strip varies fastest within an XCD -> A slice 1MB, L2-hot).
  const int d  = blockIdx.x;
  const int L  = (d & 7) * 256 + (d >> 3);
  const int m0 = (L >> 7) * 64 + wave * 16;      // this wave's private 16 rows
  const int n0 = (L & 127) * 64;                 // block's filter tile

  f32x4 acc[4];
  #pragma unroll
  for (int j = 0; j < 4; j++) acc[j] = (f32x4){0.f, 0.f, 0.f, 0.f};

  // constant bf16 e2 fragments: lane (l16,quad) of frag (ks,j) holds
  // col f = n0+j*16+l16, k = ks*32 + quad*8 + e
  const int nrow0 = n0 + l16;
  bf16x8 e2f[2][4];
  #pragma unroll
  for (int j = 0; j < 4; j++)
    #pragma unroll
    for (int ks = 0; ks < 2; ks++) {
      const float* p = E2 + (size_t)(nrow0 + j * 16) * 64 + ks * 32 + quad * 8;
      float4 lo = *(const float4*)p, hi = *(const float4*)(p + 4);
      bf16x8 bb;
      bb[0] = (__bf16)lo.x; bb[1] = (__bf16)lo.y;
      bb[2] = (__bf16)lo.z; bb[3] = (__bf16)lo.w;
      bb[4] = (__bf16)hi.x; bb[5] = (__bf16)hi.y;
      bb[6] = (__bf16)hi.z; bb[7] = (__bf16)hi.w;
      e2f[ks][j] = bb;
    }

  // A-frag direct pointer: lane (l16,quad) reads row m0+l16,
  // cols kt*64 + ks*32 + quad*8 + (0..7)  -> one b128 per (kt,ks).
  const short* Ap = A + (size_t)(m0 + l16) * 4096 + quad * 8;
  const float* e1p = E1t + nrow0;                // + kt*8192 + j*16

  // software pipeline, distance 1 (TLP across 16 waves/CU covers L2 latency)
  bf16x8 an0 = *(const bf16x8*)(Ap);
  bf16x8 an1 = *(const bf16x8*)(Ap + 32);
  float e1n[4];
  #pragma unroll
  for (int j = 0; j < 4; j++) e1n[j] = e1p[j * 16];

  const f32x4 Z4 = (f32x4){0.f, 0.f, 0.f, 0.f};

  #pragma unroll 4
  for (int kt = 0; kt < 64; ++kt) {
    bf16x8 a0 = an0, a1 = an1;
    float e1c[4];
    #pragma unroll
    for (int j = 0; j < 4; j++) e1c[j] = e1n[j];

    const int tn = (kt + 1 > 63) ? 63 : kt + 1;  // tail: dummy reload (L2 hit)
    an0 = *(const bf16x8*)(Ap + tn * 64);
    an1 = *(const bf16x8*)(Ap + tn * 64 + 32);
    const float* ep = e1p + (size_t)tn * 8192;
    #pragma unroll
    for (int j = 0; j < 4; j++) e1n[j] = ep[j * 16];

    #pragma unroll
    for (int j = 0; j < 4; j++) {
      f32x4 P = __builtin_amdgcn_mfma_f32_16x16x32_bf16(a0, e2f[0][j], Z4, 0, 0, 0);
      P = __builtin_amdgcn_mfma_f32_16x16x32_bf16(a1, e2f[1][j], P, 0, 0, 0);
      const f32x4 s4 = (f32x4){e1c[j], e1c[j], e1c[j], e1c[j]};
      acc[j] += s4 * P;                          // f32 fold of e1 (per-lane f)
    }
  }

  // epilogue: C/D layout col=lane&15 (=f), row=quad*4+reg (m within 16)
  #pragma unroll
  for (int r = 0; r < 4; r++) {
    float* crow = C + (size_t)(m0 + quad * 4 + r) * 8192 + n0 + l16;
    #pragma unroll
    for (int j = 0; j < 4; j++) crow[j * 16] = acc[j][r];
  }
}

// ---------------- k3: row-normalize d_out (1024 rows of 8192) ----------------
__global__ __launch_bounds__(256) void norm_kernel(float* __restrict__ out) {
  const int b = blockIdx.x;
  const int t = threadIdx.x;
  const int lane = t & 63, wave = t >> 6;
  __shared__ float red[4];

  float4* row = (float4*)(out + (size_t)b * 8192);   // 2048 float4
  float4 v[8];
  float s = 0.0f;
  #pragma unroll
  for (int q = 0; q < 8; q++) {
    v[q] = row[q * 256 + t];
    s += (v[q].x + v[q].y) + (v[q].z + v[q].w);
  }
  float ws = wave_sum(s);
  if (lane == 0) red[wave] = ws;
  __syncthreads();
  float tot = (red[0] + red[1]) + (red[2] + red[3]);
  float inv = 1.0f / tot;
  #pragma unroll
  for (int q = 0; q < 8; q++) {
    v[q].x *= inv; v[q].y *= inv; v[q].z *= inv; v[q].w *= inv;
    row[q * 256 + t] = v[q];
  }
}

// ---------------------------------------------------------------------------
extern "C" void kernel_launch(void* const* d_in, const int* in_sizes, int n_in,
                              void* d_out, int out_size, void* d_ws, size_t ws_size,
                              hipStream_t stream) {
  const float* freq    = (const float*)d_in[0];   // 1024*4096
  const float* kparams = (const float*)d_in[1];   // 8192*4*6
  const float* temp    = (const float*)d_in[2];   // 1
  // d_in[3] = kmer_idcs (recomputed analytically in-kernel)

  float* out = (float*)d_out;                     // 1024*8192 f32

  short* freqb = (short*)d_ws;                    // 1024*4096 bf16 = 8 MiB
  float* E1t   = (float*)(freqb + (size_t)1024 * 4096);  // 64*8192 f32 = 2 MiB
  float* E2    = E1t + (size_t)64 * 8192;                // 8192*64 f32 = 2 MiB

  prep_kernel  <<<6144, 256, 0, stream>>>(freq, freqb, kparams, temp, E1t, E2);
  gemm_kernel  <<<2048, 256, 0, stream>>>(freqb, E1t, E2, out);
  norm_kernel  <<<1024, 256, 0, stream>>>(out);
}